// Round 13
// baseline (339.876 us; speedup 1.0000x reference)
//
#include <hip/hip_runtime.h>
#include <hip/hip_bf16.h>
#include <math.h>

#define NN   30000
#define NE   300000
#define ETOT 330000   // NE + NN self loops
#define NB   300
#define EMB  64
#define D1   256      // 4 heads * 64
#define H1   4
#define H3   6
#define O3   121
#define D3   726      // 6 * 121
#define NQ   60       // 6 heads x 10 classes (pre-projected conv3 output)
#define N3   72       // NQ + 6 (es) + 6 (ed)
#define NCLS 10

typedef __attribute__((ext_vector_type(8))) short short8;
typedef __attribute__((ext_vector_type(4))) float floatx4;

static inline int ceil_div(int a, int b) { return (a + b - 1) / b; }

__device__ inline void split_bf16(float f, unsigned short& hi, unsigned short& lo) {
    __hip_bfloat16 h = __float2bfloat16(f);
    float fh = __bfloat162float(h);
    __hip_bfloat16 l = __float2bfloat16(f - fh);
    hi = __builtin_bit_cast(unsigned short, h);
    lo = __builtin_bit_cast(unsigned short, l);
}

__device__ inline float bf2f(unsigned short u) {
    return __builtin_bit_cast(float, (unsigned int)u << 16);
}

__device__ inline unsigned short f2bf(float f) {
    return __builtin_bit_cast(unsigned short, __float2bfloat16(f));
}

__device__ inline float lrelu(float v) { return v > 0.f ? v : 0.2f * v; }

// ---------------- fused setup 1: zero + node encoder (split H0) ----------------

__global__ void setup1_kernel(const int* __restrict__ x, const int* __restrict__ dep,
                              const float* __restrict__ nemb, const float* __restrict__ demb,
                              unsigned short* __restrict__ H0hi, unsigned short* __restrict__ H0lo,
                              int* __restrict__ cnt, float* __restrict__ G,
                              int* __restrict__ gs, int* __restrict__ ge) {
    int i = blockIdx.x * blockDim.x + threadIdx.x;
    if (i < NN * EMB) {
        int n = i >> 6, d = i & 63;
        float v = nemb[x[n] * EMB + d] + demb[dep[n] * EMB + d];
        split_bf16(v, H0hi[i], H0lo[i]);
    }
    if (i < NN) cnt[i] = 0;
    if (i < NB) { gs[i] = 0; ge[i] = 0; }
    if (i < NB * NCLS) G[i] = 0.f;
}

// ---- setup 2: count + ranges + W1/W2 bf16 transpose + conv3 fold + conv1 logit fold ----

__global__ void setup2_kernel(const int* __restrict__ ei, const int* __restrict__ batch,
                              const float* __restrict__ w1, const float* __restrict__ as1,
                              const float* __restrict__ ad1,
                              const float* __restrict__ w2, const float* __restrict__ w3,
                              const float* __restrict__ as3, const float* __restrict__ ad3,
                              const float* __restrict__ wp,
                              int* __restrict__ cnt, int* __restrict__ gs, int* __restrict__ ge,
                              unsigned short* __restrict__ W1b,
                              unsigned short* __restrict__ W2b,
                              unsigned short* __restrict__ W3b,
                              float* __restrict__ vs1, float* __restrict__ vd1) {
    int i = blockIdx.x * blockDim.x + threadIdx.x;
    if (i < ETOT) {
        int dst = (i < NE) ? ei[NE + i] : (i - NE);
        atomicAdd(&cnt[dst], 1);
    }
    if (i < NN) {
        int b = batch[i];
        if (i == 0 || batch[i - 1] != b) gs[b] = i;
        if (i == NN - 1 || batch[i + 1] != b) ge[b] = i + 1;
    }
    if (i < EMB * D1) {
        int k = i / D1, n = i % D1;
        W1b[n * EMB + k] = f2bf(w1[i]);     // [out n][in k within head], k<64
    }
    if (i < D1 * D1) {
        int k = i / D1, n = i % D1;
        W2b[n * D1 + k] = f2bf(w2[i]);
    }
    if (i < N3 * D1) {
        int n = i / D1, k = i % D1;
        float acc = 0.f;
        if (n < NQ) {
            int h = n / NCLS, c = n % NCLS;
            const float* wrow = w3 + (size_t)k * D3 + h * O3;
            for (int j = 0; j < O3; j++) acc += wrow[j] * wp[j * NCLS + c];
        } else if (n < NQ + H3) {
            int h = n - NQ;
            const float* wrow = w3 + (size_t)k * D3 + h * O3;
            for (int j = 0; j < O3; j++) acc += wrow[j] * as3[h * O3 + j];
        } else {
            int h = n - NQ - H3;
            const float* wrow = w3 + (size_t)k * D3 + h * O3;
            for (int j = 0; j < O3; j++) acc += wrow[j] * ad3[h * O3 + j];
        }
        W3b[i] = f2bf(acc);
    }
    // conv1 logits fold: vs1[k][h] = sum_j w1[k, h*64+j]*as1[h,j]  (k<64,h<4)
    if (i < 512) {
        int which = i >> 8;            // 0 = vs, 1 = vd
        int j2 = i & 255;
        int k = j2 >> 2, h = j2 & 3;
        const float* av = which ? ad1 : as1;
        const float* wrow = w1 + (size_t)k * D1 + h * 64;
        float acc = 0.f;
        #pragma unroll 8
        for (int j = 0; j < 64; j++) acc += wrow[j] * av[h * 64 + j];
        if (which) vd1[k * 4 + h] = acc;
        else       vs1[k * 4 + h] = acc;
    }
}

// single-block thread-coarsened scan: 1024 threads x 30 contiguous elems
__global__ __launch_bounds__(1024) void scan_kernel(const int* __restrict__ cnt,
                                                    int* __restrict__ rowoff,
                                                    int* __restrict__ fillp) {
    const int CHUNK = 30;   // 1024*30 = 30720 >= NN
    __shared__ int wsum[16];
    int tid = threadIdx.x;
    int base = tid * CHUNK;
    int pref[CHUNK];
    int local = 0;
    #pragma unroll
    for (int i = 0; i < CHUNK; i++) {
        int idx = base + i;
        int c = (idx < NN) ? cnt[idx] : 0;
        pref[i] = local;
        local += c;
    }
    int lane = tid & 63, wave = tid >> 6;
    int incl = local;
    #pragma unroll
    for (int off2 = 1; off2 < 64; off2 <<= 1) {
        int t = __shfl_up(incl, off2);
        if (lane >= off2) incl += t;
    }
    if (lane == 63) wsum[wave] = incl;
    __syncthreads();
    if (wave == 0 && lane < 16) {
        int ws = wsum[lane];
        #pragma unroll
        for (int off2 = 1; off2 < 16; off2 <<= 1) {
            int t = __shfl_up(ws, off2);
            if (lane >= off2) ws += t;
        }
        wsum[lane] = ws;
    }
    __syncthreads();
    int waveoff = (wave > 0) ? wsum[wave - 1] : 0;
    int texcl = waveoff + incl - local;
    #pragma unroll
    for (int i = 0; i < CHUNK; i++) {
        int idx = base + i;
        if (idx < NN) {
            int e = texcl + pref[i];
            rowoff[idx] = e;
            fillp[idx]  = e;
        }
    }
    if (tid == 1023) rowoff[NN] = texcl + local;
}

// fill CSR + conv1 logits (es/ed = H0 . vs1/vd1, fp32 via hi+lo) on idle threads
__global__ void fill_kernel(const int* __restrict__ ei, int* __restrict__ fillp,
                            int* __restrict__ csr,
                            const unsigned short* __restrict__ H0hi,
                            const unsigned short* __restrict__ H0lo,
                            const float* __restrict__ vs1, const float* __restrict__ vd1,
                            float* __restrict__ es, float* __restrict__ ed) {
    int e = blockIdx.x * blockDim.x + threadIdx.x;
    if (e < ETOT) {
        int src, dst;
        if (e < NE) { src = ei[e]; dst = ei[NE + e]; }
        else        { src = e - NE; dst = e - NE; }
        int slot = atomicAdd(&fillp[dst], 1);
        csr[slot] = src;
    }
    if (e < NN * 4) {
        int n = e >> 2, h = e & 3;
        const ushort4* rh = (const ushort4*)(H0hi + (size_t)n * 64);
        const ushort4* rl = (const ushort4*)(H0lo + (size_t)n * 64);
        float s_ = 0.f, d_ = 0.f;
        #pragma unroll
        for (int d4 = 0; d4 < 16; d4++) {
            ushort4 a = rh[d4], b = rl[d4];
            float v0 = bf2f(a.x) + bf2f(b.x);
            float v1 = bf2f(a.y) + bf2f(b.y);
            float v2 = bf2f(a.z) + bf2f(b.z);
            float v3 = bf2f(a.w) + bf2f(b.w);
            int k = d4 * 4;
            s_ += v0 * vs1[(k + 0) * 4 + h] + v1 * vs1[(k + 1) * 4 + h]
                + v2 * vs1[(k + 2) * 4 + h] + v3 * vs1[(k + 3) * 4 + h];
            d_ += v0 * vd1[(k + 0) * 4 + h] + v1 * vd1[(k + 1) * 4 + h]
                + v2 * vd1[(k + 2) * 4 + h] + v3 * vd1[(k + 3) * 4 + h];
        }
        es[e] = s_;
        ed[e] = d_;
    }
}

// ---------------- conv1: aggregate H0 (64-wide bf16 hi) per head -> AH[dst, h*64+k] ----
// 4 dsts per wave, 1875 blocks co-resident. 128 B/edge gather. Output bf16 hi only.

__global__ __launch_bounds__(256) void aggregate1H_kernel(
    const unsigned short* __restrict__ H, const float* __restrict__ es,
    const float* __restrict__ ed, const int* __restrict__ rowoff,
    const int* __restrict__ csr, unsigned short* __restrict__ AH) {
    int wave = threadIdx.x >> 6, lane = threadIdx.x & 63;
    int wid = blockIdx.x * 4 + wave;
    #pragma unroll 1
    for (int t = 0; t < 4; t++) {
        int dst = wid * 4 + t;
        int s0 = rowoff[dst], s1 = rowoff[dst + 1];
        float4 edv = *(const float4*)(ed + dst * 4);
        float sum0 = 0.f, sum1 = 0.f, sum2 = 0.f, sum3 = 0.f;
        float acc0 = 0.f, acc1 = 0.f, acc2 = 0.f, acc3 = 0.f;
        int s = s0;
        for (; s + 8 <= s1; s += 8) {
            int si[8];
            #pragma unroll
            for (int u = 0; u < 8; u++) si[u] = csr[s + u];
            float4 e4[8];
            float hv[8];
            #pragma unroll
            for (int u = 0; u < 8; u++) {
                e4[u] = *(const float4*)(es + si[u] * 4);
                hv[u] = bf2f(H[(size_t)si[u] * 64 + lane]);
            }
            #pragma unroll
            for (int u = 0; u < 8; u++) {
                float e0 = __expf(lrelu(e4[u].x + edv.x));
                float e1 = __expf(lrelu(e4[u].y + edv.y));
                float e2 = __expf(lrelu(e4[u].z + edv.z));
                float e3 = __expf(lrelu(e4[u].w + edv.w));
                sum0 += e0; sum1 += e1; sum2 += e2; sum3 += e3;
                acc0 += e0 * hv[u]; acc1 += e1 * hv[u];
                acc2 += e2 * hv[u]; acc3 += e3 * hv[u];
            }
        }
        for (; s < s1; s++) {
            int sa = csr[s];
            float4 e4 = *(const float4*)(es + sa * 4);
            float hv = bf2f(H[(size_t)sa * 64 + lane]);
            float e0 = __expf(lrelu(e4.x + edv.x));
            float e1 = __expf(lrelu(e4.y + edv.y));
            float e2 = __expf(lrelu(e4.z + edv.z));
            float e3 = __expf(lrelu(e4.w + edv.w));
            sum0 += e0; sum1 += e1; sum2 += e2; sum3 += e3;
            acc0 += e0 * hv; acc1 += e1 * hv; acc2 += e2 * hv; acc3 += e3 * hv;
        }
        size_t base = (size_t)dst * D1 + lane;
        AH[base]       = f2bf(acc0 / sum0);
        AH[base + 64]  = f2bf(acc1 / sum1);
        AH[base + 128] = f2bf(acc2 / sum2);
        AH[base + 192] = f2bf(acc3 / sum3);
    }
}

// ---------------- conv1 GEMM-B: H1 = ELU(AH_blockdiag . W1 + b1), per-head K=64 ------
// Plain bf16; 128x128 tile; wave (wave&1) selects head within block.

#define LDA 40
#define LDA2 72

__global__ __launch_bounds__(256) void gemmB1_kernel(
    const unsigned short* __restrict__ A, const unsigned short* __restrict__ B,
    const float* __restrict__ bias, unsigned short* __restrict__ C) {
    __shared__ unsigned short sA[128 * LDA2];
    __shared__ unsigned short sB[128 * LDA];
    int tid = threadIdx.x;
    int lane = tid & 63, wave = tid >> 6;
    int wr = (wave >> 1) * 64, wc = (wave & 1) * 64;
    int quad = lane >> 4, mr = lane & 15;
    int row0 = blockIdx.y * 128, col0 = blockIdx.x * 128;
    int M = NN;

    floatx4 zero = {0.f, 0.f, 0.f, 0.f};
    floatx4 acc[4][4];
    #pragma unroll
    for (int i = 0; i < 4; i++)
        #pragma unroll
        for (int j = 0; j < 4; j++) acc[i][j] = zero;

    for (int k0 = 0; k0 < EMB; k0 += 32) {
        // stage A: 128 rows x 64 cols (2 heads x 32 k); c = hsel*32 + kk
        #pragma unroll
        for (int ch = 0; ch < 4; ch++) {
            int linear = (ch * 256 + tid) * 8;   // 128*64 = 8192
            int r = linear >> 6, c = linear & 63;
            int gr = row0 + r;
            int gcol = col0 + (c >> 5) * 64 + k0 + (c & 31);
            uint4 v;
            if (gr < M) v = *(const uint4*)(A + (size_t)gr * D1 + gcol);
            else        v = uint4{0, 0, 0, 0};
            *(uint4*)&sA[r * LDA2 + c] = v;
        }
        // stage B: 128 n-rows x 32 k
        #pragma unroll
        for (int ch = 0; ch < 2; ch++) {
            int linear = (ch * 256 + tid) * 8;   // 128*32 = 4096
            int r = linear >> 5, c = linear & 31;
            int gn = col0 + r;
            uint4 v = *(const uint4*)(B + (size_t)gn * EMB + k0 + c);
            *(uint4*)&sB[r * LDA + c] = v;
        }
        __syncthreads();

        short8 ah[4], bh[4];
        #pragma unroll
        for (int i = 0; i < 4; i++) {
            int ar = wr + i * 16 + mr;
            ah[i] = *(const short8*)&sA[ar * LDA2 + (wave & 1) * 32 + quad * 8];
            int br = wc + i * 16 + mr;
            bh[i] = *(const short8*)&sB[br * LDA + quad * 8];
        }
        #pragma unroll
        for (int i = 0; i < 4; i++)
            #pragma unroll
            for (int j = 0; j < 4; j++)
                acc[i][j] = __builtin_amdgcn_mfma_f32_16x16x32_bf16(ah[i], bh[j], acc[i][j], 0, 0, 0);
        __syncthreads();
    }

    #pragma unroll
    for (int i = 0; i < 4; i++) {
        #pragma unroll
        for (int j = 0; j < 4; j++) {
            int gc = col0 + wc + j * 16 + mr;
            int gr0 = row0 + wr + i * 16 + quad * 4;
            float bv = bias[gc];
            #pragma unroll
            for (int r = 0; r < 4; r++) {
                int gr = gr0 + r;
                if (gr >= M) continue;
                float v = acc[i][j][r] + bv;
                v = v > 0.f ? v : expm1f(v);
                C[(size_t)gr * D1 + gc] = f2bf(v);
            }
        }
    }
}

// ---------------- MFMA GEMM (plain bf16): C[MxN] = A[MxK] * BT[NxK]^T ----------------
// MODE 0: bf16 P out (N=256) + fused es/ed logits epilogue (as_/ad_ [4][64]).
// MODE 1: bf16 Q[.,60] + fp32 es[.,6] + ed[.,6] (conv3 pre-folded B).

template <int MODE>
__global__ __launch_bounds__(256) void gemm_mfma_kernel(
    const unsigned short* __restrict__ A, const unsigned short* __restrict__ B,
    unsigned short* __restrict__ Cbf, unsigned short* __restrict__ Qb,
    float* __restrict__ es, float* __restrict__ ed,
    const float* __restrict__ as_, const float* __restrict__ ad_,
    int M, int K, int N) {
    __shared__ unsigned short sA[128 * LDA], sB[128 * LDA];
    int tid = threadIdx.x;
    int lane = tid & 63, wave = tid >> 6;
    int wr = (wave >> 1) * 64, wc = (wave & 1) * 64;
    int quad = lane >> 4, mr = lane & 15;
    int row0 = blockIdx.y * 128, col0 = blockIdx.x * 128;

    floatx4 zero = {0.f, 0.f, 0.f, 0.f};
    floatx4 acc[4][4];
    #pragma unroll
    for (int i = 0; i < 4; i++)
        #pragma unroll
        for (int j = 0; j < 4; j++) acc[i][j] = zero;

    for (int k0 = 0; k0 < K; k0 += 32) {
        #pragma unroll
        for (int ch = 0; ch < 2; ch++) {
            int linear = (ch * 256 + tid) * 8;   // 128*32 = 4096 elements
            int r = linear >> 5, c = linear & 31;
            uint4 v;
            int gr = row0 + r;
            if (gr < M) v = *(const uint4*)(A + (size_t)gr * K + k0 + c);
            else        v = uint4{0, 0, 0, 0};
            *(uint4*)&sA[r * LDA + c] = v;
            int gn = col0 + r;
            if (gn < N) v = *(const uint4*)(B + (size_t)gn * K + k0 + c);
            else        v = uint4{0, 0, 0, 0};
            *(uint4*)&sB[r * LDA + c] = v;
        }
        __syncthreads();

        short8 ah[4], bh[4];
        #pragma unroll
        for (int i = 0; i < 4; i++) {
            int ar = wr + i * 16 + mr;
            ah[i] = *(const short8*)&sA[ar * LDA + quad * 8];
            int br = wc + i * 16 + mr;
            bh[i] = *(const short8*)&sB[br * LDA + quad * 8];
        }
        #pragma unroll
        for (int i = 0; i < 4; i++)
            #pragma unroll
            for (int j = 0; j < 4; j++)
                acc[i][j] = __builtin_amdgcn_mfma_f32_16x16x32_bf16(ah[i], bh[j], acc[i][j], 0, 0, 0);
        __syncthreads();
    }

    #pragma unroll
    for (int i = 0; i < 4; i++) {
        #pragma unroll
        for (int j = 0; j < 4; j++) {
            int gc = col0 + wc + j * 16 + mr;
            if (gc >= N) continue;
            int gr0 = row0 + wr + i * 16 + quad * 4;
            #pragma unroll
            for (int r = 0; r < 4; r++) {
                int gr = gr0 + r;
                if (gr >= M) continue;
                float v = acc[i][j][r];
                if (MODE == 0) {
                    Cbf[(size_t)gr * D1 + gc] = f2bf(v);
                } else {
                    if (gc < NQ)            Qb[(size_t)gr * NQ + gc] = f2bf(v);
                    else if (gc < NQ + H3)  es[(size_t)gr * H3 + (gc - NQ)] = v;
                    else                    ed[(size_t)gr * H3 + (gc - NQ - H3)] = v;
                }
            }
        }
    }

    if (MODE == 0) {
        // fused logits: this wave owns head hx for rows wr..wr+63
        int hx = 2 * blockIdx.x + (wave & 1);
        float asr[4], adr[4];
        #pragma unroll
        for (int j = 0; j < 4; j++) {
            asr[j] = as_[hx * 64 + j * 16 + mr];
            adr[j] = ad_[hx * 64 + j * 16 + mr];
        }
        #pragma unroll
        for (int i = 0; i < 4; i++) {
            #pragma unroll
            for (int r = 0; r < 4; r++) {
                float ps = 0.f, pd = 0.f;
                #pragma unroll
                for (int j = 0; j < 4; j++) {
                    float v = acc[i][j][r];
                    ps += v * asr[j];
                    pd += v * adr[j];
                }
                #pragma unroll
                for (int m2 = 8; m2 >= 1; m2 >>= 1) {
                    ps += __shfl_xor(ps, m2);
                    pd += __shfl_xor(pd, m2);
                }
                int gr = row0 + wr + i * 16 + quad * 4 + r;
                if (mr == 0 && gr < M) {
                    es[gr * 4 + hx] = ps;
                    ed[gr * 4 + hx] = pd;
                }
            }
        }
    }
}

// ---------------- conv2: one-pass max-free softmax aggregation ----------------
// 4 dsts per wave, 1875 blocks (co-resident); 8/4/2/1-edge unroll; bf16 hi out.

__global__ __launch_bounds__(256) void aggregate12_kernel(
    const unsigned short* __restrict__ P, const float* __restrict__ es,
    const float* __restrict__ ed, const int* __restrict__ rowoff,
    const int* __restrict__ csr, const float* __restrict__ bias,
    unsigned short* __restrict__ outHi) {
    int wave = threadIdx.x >> 6, lane = threadIdx.x & 63;
    int wid = blockIdx.x * 4 + wave;
    int head = lane >> 4;
    int f0 = lane * 4;
    float bv0 = bias[f0], bv1 = bias[f0 + 1], bv2 = bias[f0 + 2], bv3 = bias[f0 + 3];
    #pragma unroll 1
    for (int t = 0; t < 4; t++) {
        int dst = wid * 4 + t;
        int s0 = rowoff[dst], s1 = rowoff[dst + 1];
        float edv = ed[dst * 4 + head];
        float sum = 0.f;
        float acc0 = 0.f, acc1 = 0.f, acc2 = 0.f, acc3 = 0.f;
        int s = s0;
        for (; s + 8 <= s1; s += 8) {
            int si[8];
            #pragma unroll
            for (int u = 0; u < 8; u++) si[u] = csr[s + u];
            float vv[8];
            ushort4 pp[8];
            #pragma unroll
            for (int u = 0; u < 8; u++) {
                vv[u] = es[si[u] * 4 + head] + edv;
                pp[u] = *(const ushort4*)(P + (size_t)si[u] * D1 + f0);
            }
            #pragma unroll
            for (int u = 0; u < 8; u++) {
                float e = __expf(lrelu(vv[u]));
                sum += e;
                acc0 += e * bf2f(pp[u].x);
                acc1 += e * bf2f(pp[u].y);
                acc2 += e * bf2f(pp[u].z);
                acc3 += e * bf2f(pp[u].w);
            }
        }
        for (; s + 4 <= s1; s += 4) {
            int sa = csr[s], sb = csr[s + 1], sc = csr[s + 2], sd = csr[s + 3];
            float va = es[sa * 4 + head] + edv;
            float vb = es[sb * 4 + head] + edv;
            float vc = es[sc * 4 + head] + edv;
            float vd = es[sd * 4 + head] + edv;
            ushort4 pa = *(const ushort4*)(P + (size_t)sa * D1 + f0);
            ushort4 pb = *(const ushort4*)(P + (size_t)sb * D1 + f0);
            ushort4 pc = *(const ushort4*)(P + (size_t)sc * D1 + f0);
            ushort4 pd = *(const ushort4*)(P + (size_t)sd * D1 + f0);
            float ea = __expf(lrelu(va));
            float eb = __expf(lrelu(vb));
            float ec = __expf(lrelu(vc));
            float ee = __expf(lrelu(vd));
            sum += (ea + eb) + (ec + ee);
            acc0 += ea * bf2f(pa.x) + eb * bf2f(pb.x) + ec * bf2f(pc.x) + ee * bf2f(pd.x);
            acc1 += ea * bf2f(pa.y) + eb * bf2f(pb.y) + ec * bf2f(pc.y) + ee * bf2f(pd.y);
            acc2 += ea * bf2f(pa.z) + eb * bf2f(pb.z) + ec * bf2f(pc.z) + ee * bf2f(pd.z);
            acc3 += ea * bf2f(pa.w) + eb * bf2f(pb.w) + ec * bf2f(pc.w) + ee * bf2f(pd.w);
        }
        for (; s + 2 <= s1; s += 2) {
            int sa = csr[s], sb = csr[s + 1];
            float va = es[sa * 4 + head] + edv;
            float vb = es[sb * 4 + head] + edv;
            ushort4 pa = *(const ushort4*)(P + (size_t)sa * D1 + f0);
            ushort4 pb = *(const ushort4*)(P + (size_t)sb * D1 + f0);
            float ea = __expf(lrelu(va));
            float eb = __expf(lrelu(vb));
            sum += ea + eb;
            acc0 += ea * bf2f(pa.x) + eb * bf2f(pb.x);
            acc1 += ea * bf2f(pa.y) + eb * bf2f(pb.y);
            acc2 += ea * bf2f(pa.z) + eb * bf2f(pb.z);
            acc3 += ea * bf2f(pa.w) + eb * bf2f(pb.w);
        }
        for (; s < s1; s++) {
            int sa = csr[s];
            float va = es[sa * 4 + head] + edv;
            ushort4 pa = *(const ushort4*)(P + (size_t)sa * D1 + f0);
            float ea = __expf(lrelu(va));
            sum += ea;
            acc0 += ea * bf2f(pa.x);
            acc1 += ea * bf2f(pa.y);
            acc2 += ea * bf2f(pa.z);
            acc3 += ea * bf2f(pa.w);
        }
        float inv = 1.f / sum;
        float a0 = acc0 * inv + bv0;
        float a1 = acc1 * inv + bv1;
        float a2 = acc2 * inv + bv2;
        float a3 = acc3 * inv + bv3;
        a0 = a0 > 0.f ? a0 : expm1f(a0);
        a1 = a1 > 0.f ? a1 : expm1f(a1);
        a2 = a2 > 0.f ? a2 : expm1f(a2);
        a3 = a3 > 0.f ? a3 : expm1f(a3);
        ushort4 hi4;
        hi4.x = f2bf(a0); hi4.y = f2bf(a1); hi4.z = f2bf(a2); hi4.w = f2bf(a3);
        *(ushort4*)(outHi + (size_t)dst * D1 + f0) = hi4;
    }
}

// ---------------- conv3: one-pass softmax + bf16 Q-gather + pool/classify ----------

__global__ __launch_bounds__(256) void aggregate3q_kernel(
    const unsigned short* __restrict__ Qb, const float* __restrict__ es,
    const float* __restrict__ ed, const int* __restrict__ rowoff,
    const int* __restrict__ csr, const int* __restrict__ batch,
    float* __restrict__ G) {
    int wave = threadIdx.x >> 6, lane = threadIdx.x & 63;
    int wid = blockIdx.x * 4 + wave;
    bool act = lane < NQ;
    int h = act ? (lane / NCLS) : 0;
    int q = act ? lane : 0;
    #pragma unroll 1
    for (int t = 0; t < 4; t++) {
        int dst = wid * 4 + t;
        int b = batch[dst];
        int s0 = rowoff[dst], s1 = rowoff[dst + 1];
        float edv = act ? ed[dst * H3 + h] : 0.f;
        float sum = 0.f, acc = 0.f;
        int s = s0;
        for (; s + 8 <= s1; s += 8) {
            int si[8];
            #pragma unroll
            for (int u = 0; u < 8; u++) si[u] = csr[s + u];
            float vv[8], qq[8];
            #pragma unroll
            for (int u = 0; u < 8; u++) {
                vv[u] = es[si[u] * H3 + h] + edv;
                qq[u] = bf2f(Qb[(size_t)si[u] * NQ + q]);
            }
            #pragma unroll
            for (int u = 0; u < 8; u++) {
                float e = __expf(lrelu(vv[u]));
                sum += e;
                acc += e * qq[u];
            }
        }
        for (; s + 2 <= s1; s += 2) {
            int sa = csr[s], sb = csr[s + 1];
            float va = es[sa * H3 + h] + edv;
            float vb = es[sb * H3 + h] + edv;
            float qa = bf2f(Qb[(size_t)sa * NQ + q]);
            float qb = bf2f(Qb[(size_t)sb * NQ + q]);
            float ea = __expf(lrelu(va));
            float eb = __expf(lrelu(vb));
            sum += ea + eb;
            acc += ea * qa + eb * qb;
        }
        for (; s < s1; s++) {
            int sa = csr[s];
            float va = es[sa * H3 + h] + edv;
            float qa = bf2f(Qb[(size_t)sa * NQ + q]);
            float ea = __expf(lrelu(va));
            sum += ea;
            acc += ea * qa;
        }
        acc *= 1.f / sum;
        float av = act ? acc : 0.f;
        float tot = av;
        #pragma unroll
        for (int h2 = 1; h2 < H3; h2++) tot += __shfl(av, lane + h2 * NCLS);
        if (lane < NCLS) atomicAdd(&G[b * NCLS + lane], tot);
    }
}

// ---------------- final: per-graph mean + folded b3 bias + bp ----------------

__global__ __launch_bounds__(64) void final_kernel(
    const float* __restrict__ G, const int* __restrict__ gs, const int* __restrict__ ge,
    const float* __restrict__ b3, const float* __restrict__ wp,
    const float* __restrict__ bp, float* __restrict__ out) {
    int b = blockIdx.x, tid = threadIdx.x;
    if (tid >= NCLS) return;
    int cntn = ge[b] - gs[b];
    float o = bp[tid];
    if (cntn > 0) {
        float bt = 0.f;
        for (int k = 0; k < O3; k++) {
            float bs = 0.f;
            #pragma unroll
            for (int h = 0; h < H3; h++) bs += b3[h * O3 + k];
            bt += bs * wp[k * NCLS + tid];
        }
        o += G[b * NCLS + tid] / (6.f * (float)cntn) + bt * (1.f / 6.f);
    }
    out[b * NCLS + tid] = o;
}

// ---------------- launch ----------------

extern "C" void kernel_launch(void* const* d_in, const int* in_sizes, int n_in,
                              void* d_out, int out_size, void* d_ws, size_t ws_size,
                              hipStream_t stream) {
    const int* x     = (const int*)d_in[0];
    const int* dep   = (const int*)d_in[1];
    const int* ei    = (const int*)d_in[2];
    const int* batch = (const int*)d_in[3];
    const float* nemb = (const float*)d_in[4];
    const float* demb = (const float*)d_in[5];
    const float* w1  = (const float*)d_in[6];
    const float* as1 = (const float*)d_in[7];
    const float* ad1 = (const float*)d_in[8];
    const float* b1  = (const float*)d_in[9];
    const float* w2  = (const float*)d_in[10];
    const float* as2 = (const float*)d_in[11];
    const float* ad2 = (const float*)d_in[12];
    const float* b2  = (const float*)d_in[13];
    const float* w3  = (const float*)d_in[14];
    const float* as3 = (const float*)d_in[15];
    const float* ad3 = (const float*)d_in[16];
    const float* b3  = (const float*)d_in[17];
    const float* wp  = (const float*)d_in[18];
    const float* bp  = (const float*)d_in[19];
    float* out = (float*)d_out;

    char* ws = (char*)d_ws;
    size_t off = 0;
    auto alloc = [&](size_t bytes) -> void* {
        void* p = ws + off;
        off += (bytes + 255) & ~(size_t)255;
        return p;
    };
    unsigned short* Hb   = (unsigned short*)alloc((size_t)NN * D1 * 2);     // H0 (stride 64) then H1/H2 (stride 256)
    unsigned short* H0lo = (unsigned short*)alloc((size_t)NN * EMB * 2);
    unsigned short* W1b  = (unsigned short*)alloc((size_t)D1 * EMB * 2);
    unsigned short* W2b  = (unsigned short*)alloc((size_t)D1 * D1 * 2);
    unsigned short* W3b  = (unsigned short*)alloc((size_t)N3 * D1 * 2);
    unsigned short* Pb   = (unsigned short*)alloc((size_t)NN * D1 * 2);     // AH (conv1) then P2 (conv2)
    unsigned short* Qb   = (unsigned short*)alloc(((size_t)NN * NQ + 64) * 2);
    float* G    = (float*)alloc((size_t)NB * NCLS * 4);
    float* es   = (float*)alloc((size_t)NN * 6 * 4);
    float* ed   = (float*)alloc((size_t)NN * 6 * 4);
    float* vs1  = (float*)alloc((size_t)EMB * 4 * 4);
    float* vd1  = (float*)alloc((size_t)EMB * 4 * 4);
    int* cnt    = (int*)alloc((size_t)NN * 4);
    int* rowoff = (int*)alloc((size_t)(NN + 1) * 4);
    int* fillp  = (int*)alloc((size_t)NN * 4);
    int* csr    = (int*)alloc((size_t)ETOT * 4);
    int* gs     = (int*)alloc((size_t)NB * 4);
    int* ge     = (int*)alloc((size_t)NB * 4);

    // --- fused preprocessing + scan + fill(+conv1 logits) ---
    setup1_kernel<<<ceil_div(NN * EMB, 256), 256, 0, stream>>>(
        x, dep, nemb, demb, Hb, H0lo, cnt, G, gs, ge);
    setup2_kernel<<<ceil_div(ETOT, 256), 256, 0, stream>>>(
        ei, batch, w1, as1, ad1, w2, w3, as3, ad3, wp,
        cnt, gs, ge, W1b, W2b, W3b, vs1, vd1);
    scan_kernel<<<1, 1024, 0, stream>>>(cnt, rowoff, fillp);
    fill_kernel<<<ceil_div(ETOT, 256), 256, 0, stream>>>(
        ei, fillp, csr, Hb, H0lo, vs1, vd1, es, ed);

    // --- conv1 (aggregate-first): gather H0 (128 B/edge) -> AH, per-head bf16 GEMM ---
    aggregate1H_kernel<<<NN / 16, 256, 0, stream>>>(Hb, es, ed, rowoff, csr, Pb);
    gemmB1_kernel<<<dim3(2, ceil_div(NN, 128)), 256, 0, stream>>>(Pb, W1b, b1, Hb);

    // --- conv2: [NN,256] -> [NN,256] plain bf16 GEMM, logits fused ---
    gemm_mfma_kernel<0><<<dim3(2, ceil_div(NN, 128)), 256, 0, stream>>>(
        Hb, W2b, Pb, nullptr, es, ed, as2, ad2, NN, D1, D1);
    aggregate12_kernel<<<NN / 16, 256, 0, stream>>>(Pb, es, ed, rowoff, csr, b2, Hb);

    // --- conv3 folded: [NN,256] -> Qb[NN,60](bf16) + es/ed[NN,6], softmax+pool fused ---
    gemm_mfma_kernel<1><<<dim3(1, ceil_div(NN, 128)), 256, 0, stream>>>(
        Hb, W3b, nullptr, Qb, es, ed, nullptr, nullptr, NN, D1, N3);
    aggregate3q_kernel<<<NN / 16, 256, 0, stream>>>(Qb, es, ed, rowoff, csr, batch, G);

    // --- final classifier ---
    final_kernel<<<NB, 64, 0, stream>>>(G, gs, ge, b3, wp, bp, out);
}

// Round 14
// 324.732 us; speedup vs baseline: 1.0466x; 1.0466x over previous
//
#include <hip/hip_runtime.h>
#include <hip/hip_bf16.h>
#include <math.h>

#define NN   30000
#define NE   300000
#define ETOT 330000   // NE + NN self loops
#define NB   300
#define EMB  64
#define D1   256      // 4 heads * 64
#define H1   4
#define H3   6
#define O3   121
#define D3   726      // 6 * 121
#define NQ   60       // 6 heads x 10 classes (pre-projected conv3 output)
#define N3   72       // NQ + 6 (es) + 6 (ed)
#define NCLS 10

typedef __attribute__((ext_vector_type(8))) short short8;
typedef __attribute__((ext_vector_type(4))) float floatx4;

static inline int ceil_div(int a, int b) { return (a + b - 1) / b; }

__device__ inline void split_bf16(float f, unsigned short& hi, unsigned short& lo) {
    __hip_bfloat16 h = __float2bfloat16(f);
    float fh = __bfloat162float(h);
    __hip_bfloat16 l = __float2bfloat16(f - fh);
    hi = __builtin_bit_cast(unsigned short, h);
    lo = __builtin_bit_cast(unsigned short, l);
}

__device__ inline float bf2f(unsigned short u) {
    return __builtin_bit_cast(float, (unsigned int)u << 16);
}

__device__ inline unsigned short f2bf(float f) {
    return __builtin_bit_cast(unsigned short, __float2bfloat16(f));
}

__device__ inline float lrelu(float v) { return v > 0.f ? v : 0.2f * v; }

// ---------------- fused setup 1: zero + node encoder + conv1 weight split ----------------

__global__ void setup1_kernel(const int* __restrict__ x, const int* __restrict__ dep,
                              const float* __restrict__ nemb, const float* __restrict__ demb,
                              const float* __restrict__ w1,
                              unsigned short* __restrict__ H0hi, unsigned short* __restrict__ H0lo,
                              unsigned short* __restrict__ W1hi, unsigned short* __restrict__ W1lo,
                              int* __restrict__ cnt, float* __restrict__ G,
                              int* __restrict__ gs, int* __restrict__ ge) {
    int i = blockIdx.x * blockDim.x + threadIdx.x;
    if (i < NN * EMB) {
        int n = i >> 6, d = i & 63;
        float v = nemb[x[n] * EMB + d] + demb[dep[n] * EMB + d];
        split_bf16(v, H0hi[i], H0lo[i]);
    }
    if (i < NN) cnt[i] = 0;
    if (i < NB) { gs[i] = 0; ge[i] = 0; }
    if (i < NB * NCLS) G[i] = 0.f;
    if (i < EMB * D1) {
        int k = i / D1, n = i % D1;
        unsigned short h, l;
        split_bf16(w1[i], h, l);
        W1hi[n * EMB + k] = h;
        W1lo[n * EMB + k] = l;
    }
}

// ---- fused setup 2: count + ranges + conv2 bf16 transpose + conv3 fold (bf16) ----

__global__ void setup2_kernel(const int* __restrict__ ei, const int* __restrict__ batch,
                              const float* __restrict__ w2, const float* __restrict__ w3,
                              const float* __restrict__ as3, const float* __restrict__ ad3,
                              const float* __restrict__ wp,
                              int* __restrict__ cnt, int* __restrict__ gs, int* __restrict__ ge,
                              unsigned short* __restrict__ W2b,
                              unsigned short* __restrict__ W3b) {
    int i = blockIdx.x * blockDim.x + threadIdx.x;
    if (i < ETOT) {
        int dst = (i < NE) ? ei[NE + i] : (i - NE);
        atomicAdd(&cnt[dst], 1);
    }
    if (i < NN) {
        int b = batch[i];
        if (i == 0 || batch[i - 1] != b) gs[b] = i;
        if (i == NN - 1 || batch[i + 1] != b) ge[b] = i + 1;
    }
    if (i < D1 * D1) {
        int k = i / D1, n = i % D1;
        W2b[n * D1 + k] = f2bf(w2[i]);
    }
    if (i < N3 * D1) {
        int n = i / D1, k = i % D1;
        float acc = 0.f;
        if (n < NQ) {
            int h = n / NCLS, c = n % NCLS;
            const float* wrow = w3 + (size_t)k * D3 + h * O3;
            for (int j = 0; j < O3; j++) acc += wrow[j] * wp[j * NCLS + c];
        } else if (n < NQ + H3) {
            int h = n - NQ;
            const float* wrow = w3 + (size_t)k * D3 + h * O3;
            for (int j = 0; j < O3; j++) acc += wrow[j] * as3[h * O3 + j];
        } else {
            int h = n - NQ - H3;
            const float* wrow = w3 + (size_t)k * D3 + h * O3;
            for (int j = 0; j < O3; j++) acc += wrow[j] * ad3[h * O3 + j];
        }
        W3b[i] = f2bf(acc);
    }
}

// single-block thread-coarsened scan: 1024 threads x 30 contiguous elems
__global__ __launch_bounds__(1024) void scan_kernel(const int* __restrict__ cnt,
                                                    int* __restrict__ rowoff,
                                                    int* __restrict__ fillp) {
    const int CHUNK = 30;   // 1024*30 = 30720 >= NN
    __shared__ int wsum[16];
    int tid = threadIdx.x;
    int base = tid * CHUNK;
    int pref[CHUNK];
    int local = 0;
    #pragma unroll
    for (int i = 0; i < CHUNK; i++) {
        int idx = base + i;
        int c = (idx < NN) ? cnt[idx] : 0;
        pref[i] = local;
        local += c;
    }
    int lane = tid & 63, wave = tid >> 6;
    int incl = local;
    #pragma unroll
    for (int off2 = 1; off2 < 64; off2 <<= 1) {
        int t = __shfl_up(incl, off2);
        if (lane >= off2) incl += t;
    }
    if (lane == 63) wsum[wave] = incl;
    __syncthreads();
    if (wave == 0 && lane < 16) {
        int ws = wsum[lane];
        #pragma unroll
        for (int off2 = 1; off2 < 16; off2 <<= 1) {
            int t = __shfl_up(ws, off2);
            if (lane >= off2) ws += t;
        }
        wsum[lane] = ws;
    }
    __syncthreads();
    int waveoff = (wave > 0) ? wsum[wave - 1] : 0;
    int texcl = waveoff + incl - local;
    #pragma unroll
    for (int i = 0; i < CHUNK; i++) {
        int idx = base + i;
        if (idx < NN) {
            int e = texcl + pref[i];
            rowoff[idx] = e;
            fillp[idx]  = e;
        }
    }
    if (tid == 1023) rowoff[NN] = texcl + local;
}

__global__ void fill_kernel(const int* __restrict__ ei, int* __restrict__ fillp,
                            int* __restrict__ csr) {
    int e = blockIdx.x * blockDim.x + threadIdx.x;
    if (e >= ETOT) return;
    int src, dst;
    if (e < NE) { src = ei[e]; dst = ei[NE + e]; }
    else        { src = e - NE; dst = e - NE; }
    int slot = atomicAdd(&fillp[dst], 1);
    csr[slot] = src;
}

// ---------------- MFMA GEMM: C[MxN] = A[MxK] * BT[NxK]^T ----------------
// SPLIT=true : split-bf16 A and B (3 MFMA per frag) — conv1 only.
// SPLIT=false: plain bf16 A and B (1 MFMA per frag) — conv2/conv3.
// MODE 0: bf16 P out (N=256) + fused es/ed logits epilogue (as_/ad_ [4][64]).
// MODE 1: bf16 Q[.,60] + fp32 es[.,6] + ed[.,6] (conv3 pre-folded B).

#define LDA 40

template <int MODE, bool SPLIT>
__global__ __launch_bounds__(256) void gemm_mfma_kernel(
    const unsigned short* __restrict__ Ahi, const unsigned short* __restrict__ Alo,
    const unsigned short* __restrict__ Bhi, const unsigned short* __restrict__ Blo,
    unsigned short* __restrict__ Cbf, unsigned short* __restrict__ Qb,
    float* __restrict__ es, float* __restrict__ ed,
    const float* __restrict__ as_, const float* __restrict__ ad_,
    int M, int K, int N) {
    __shared__ unsigned short sAh[128 * LDA], sBh[128 * LDA];
    __shared__ unsigned short sAl[SPLIT ? 128 * LDA : 1], sBl[SPLIT ? 128 * LDA : 1];
    int tid = threadIdx.x;
    int lane = tid & 63, wave = tid >> 6;
    int wr = (wave >> 1) * 64, wc = (wave & 1) * 64;
    int quad = lane >> 4, mr = lane & 15;
    int row0 = blockIdx.y * 128, col0 = blockIdx.x * 128;

    floatx4 zero = {0.f, 0.f, 0.f, 0.f};
    floatx4 acc[4][4];
    #pragma unroll
    for (int i = 0; i < 4; i++)
        #pragma unroll
        for (int j = 0; j < 4; j++) acc[i][j] = zero;

    for (int k0 = 0; k0 < K; k0 += 32) {
        #pragma unroll
        for (int ch = 0; ch < 2; ch++) {
            int linear = (ch * 256 + tid) * 8;   // 128*32 = 4096 elements
            int r = linear >> 5, c = linear & 31;
            uint4 vh, vl;
            int gr = row0 + r;
            if (gr < M) {
                vh = *(const uint4*)(Ahi + (size_t)gr * K + k0 + c);
                if (SPLIT) vl = *(const uint4*)(Alo + (size_t)gr * K + k0 + c);
            } else { vh = uint4{0, 0, 0, 0}; vl = uint4{0, 0, 0, 0}; }
            *(uint4*)&sAh[r * LDA + c] = vh;
            if (SPLIT) *(uint4*)&sAl[r * LDA + c] = vl;
            int gn = col0 + r;
            if (gn < N) {
                vh = *(const uint4*)(Bhi + (size_t)gn * K + k0 + c);
                if (SPLIT) vl = *(const uint4*)(Blo + (size_t)gn * K + k0 + c);
            } else { vh = uint4{0, 0, 0, 0}; vl = uint4{0, 0, 0, 0}; }
            *(uint4*)&sBh[r * LDA + c] = vh;
            if (SPLIT) *(uint4*)&sBl[r * LDA + c] = vl;
        }
        __syncthreads();

        short8 ah[4], al[4], bh[4], bl[4];
        #pragma unroll
        for (int i = 0; i < 4; i++) {
            int ar = wr + i * 16 + mr;
            ah[i] = *(const short8*)&sAh[ar * LDA + quad * 8];
            if (SPLIT) al[i] = *(const short8*)&sAl[ar * LDA + quad * 8];
            int br = wc + i * 16 + mr;
            bh[i] = *(const short8*)&sBh[br * LDA + quad * 8];
            if (SPLIT) bl[i] = *(const short8*)&sBl[br * LDA + quad * 8];
        }
        #pragma unroll
        for (int i = 0; i < 4; i++)
            #pragma unroll
            for (int j = 0; j < 4; j++) {
                acc[i][j] = __builtin_amdgcn_mfma_f32_16x16x32_bf16(ah[i], bh[j], acc[i][j], 0, 0, 0);
                if (SPLIT) {
                    acc[i][j] = __builtin_amdgcn_mfma_f32_16x16x32_bf16(ah[i], bl[j], acc[i][j], 0, 0, 0);
                    acc[i][j] = __builtin_amdgcn_mfma_f32_16x16x32_bf16(al[i], bh[j], acc[i][j], 0, 0, 0);
                }
            }
        __syncthreads();
    }

    #pragma unroll
    for (int i = 0; i < 4; i++) {
        #pragma unroll
        for (int j = 0; j < 4; j++) {
            int gc = col0 + wc + j * 16 + mr;
            if (gc >= N) continue;
            int gr0 = row0 + wr + i * 16 + quad * 4;
            #pragma unroll
            for (int r = 0; r < 4; r++) {
                int gr = gr0 + r;
                if (gr >= M) continue;
                float v = acc[i][j][r];
                if (MODE == 0) {
                    Cbf[(size_t)gr * D1 + gc] = f2bf(v);
                } else {
                    if (gc < NQ)            Qb[(size_t)gr * NQ + gc] = f2bf(v);
                    else if (gc < NQ + H3)  es[(size_t)gr * H3 + (gc - NQ)] = v;
                    else                    ed[(size_t)gr * H3 + (gc - NQ - H3)] = v;
                }
            }
        }
    }

    if (MODE == 0) {
        // fused logits: this wave owns head hx for rows wr..wr+63
        int hx = 2 * blockIdx.x + (wave & 1);
        float asr[4], adr[4];
        #pragma unroll
        for (int j = 0; j < 4; j++) {
            asr[j] = as_[hx * 64 + j * 16 + mr];
            adr[j] = ad_[hx * 64 + j * 16 + mr];
        }
        #pragma unroll
        for (int i = 0; i < 4; i++) {
            #pragma unroll
            for (int r = 0; r < 4; r++) {
                float ps = 0.f, pd = 0.f;
                #pragma unroll
                for (int j = 0; j < 4; j++) {
                    float v = acc[i][j][r];
                    ps += v * asr[j];
                    pd += v * adr[j];
                }
                #pragma unroll
                for (int m2 = 8; m2 >= 1; m2 >>= 1) {
                    ps += __shfl_xor(ps, m2);
                    pd += __shfl_xor(pd, m2);
                }
                int gr = row0 + wr + i * 16 + quad * 4 + r;
                if (mr == 0 && gr < M) {
                    es[gr * 4 + hx] = ps;
                    ed[gr * 4 + hx] = pd;
                }
            }
        }
    }
}

// ---------------- conv1/2: one-pass max-free softmax aggregation ----------------
// 4 dsts per wave, 1875 blocks (whole grid co-resident); 8/4/2/1-edge unroll.
// Output: bf16 hi only (consumers are plain-bf16 GEMMs).

__global__ __launch_bounds__(256) void aggregate12_kernel(
    const unsigned short* __restrict__ P, const float* __restrict__ es,
    const float* __restrict__ ed, const int* __restrict__ rowoff,
    const int* __restrict__ csr, const float* __restrict__ bias,
    unsigned short* __restrict__ outHi) {
    int wave = threadIdx.x >> 6, lane = threadIdx.x & 63;
    int wid = blockIdx.x * 4 + wave;
    int head = lane >> 4;
    int f0 = lane * 4;
    float bv0 = bias[f0], bv1 = bias[f0 + 1], bv2 = bias[f0 + 2], bv3 = bias[f0 + 3];
    #pragma unroll 1
    for (int t = 0; t < 4; t++) {
        int dst = wid * 4 + t;
        int s0 = rowoff[dst], s1 = rowoff[dst + 1];
        float edv = ed[dst * 4 + head];
        float sum = 0.f;
        float acc0 = 0.f, acc1 = 0.f, acc2 = 0.f, acc3 = 0.f;
        int s = s0;
        for (; s + 8 <= s1; s += 8) {
            int si[8];
            #pragma unroll
            for (int u = 0; u < 8; u++) si[u] = csr[s + u];
            float vv[8];
            ushort4 pp[8];
            #pragma unroll
            for (int u = 0; u < 8; u++) {
                vv[u] = es[si[u] * 4 + head] + edv;
                pp[u] = *(const ushort4*)(P + (size_t)si[u] * D1 + f0);
            }
            #pragma unroll
            for (int u = 0; u < 8; u++) {
                float e = __expf(lrelu(vv[u]));
                sum += e;
                acc0 += e * bf2f(pp[u].x);
                acc1 += e * bf2f(pp[u].y);
                acc2 += e * bf2f(pp[u].z);
                acc3 += e * bf2f(pp[u].w);
            }
        }
        for (; s + 4 <= s1; s += 4) {
            int sa = csr[s], sb = csr[s + 1], sc = csr[s + 2], sd = csr[s + 3];
            float va = es[sa * 4 + head] + edv;
            float vb = es[sb * 4 + head] + edv;
            float vc = es[sc * 4 + head] + edv;
            float vd = es[sd * 4 + head] + edv;
            ushort4 pa = *(const ushort4*)(P + (size_t)sa * D1 + f0);
            ushort4 pb = *(const ushort4*)(P + (size_t)sb * D1 + f0);
            ushort4 pc = *(const ushort4*)(P + (size_t)sc * D1 + f0);
            ushort4 pd = *(const ushort4*)(P + (size_t)sd * D1 + f0);
            float ea = __expf(lrelu(va));
            float eb = __expf(lrelu(vb));
            float ec = __expf(lrelu(vc));
            float ee = __expf(lrelu(vd));
            sum += (ea + eb) + (ec + ee);
            acc0 += ea * bf2f(pa.x) + eb * bf2f(pb.x) + ec * bf2f(pc.x) + ee * bf2f(pd.x);
            acc1 += ea * bf2f(pa.y) + eb * bf2f(pb.y) + ec * bf2f(pc.y) + ee * bf2f(pd.y);
            acc2 += ea * bf2f(pa.z) + eb * bf2f(pb.z) + ec * bf2f(pc.z) + ee * bf2f(pd.z);
            acc3 += ea * bf2f(pa.w) + eb * bf2f(pb.w) + ec * bf2f(pc.w) + ee * bf2f(pd.w);
        }
        for (; s + 2 <= s1; s += 2) {
            int sa = csr[s], sb = csr[s + 1];
            float va = es[sa * 4 + head] + edv;
            float vb = es[sb * 4 + head] + edv;
            ushort4 pa = *(const ushort4*)(P + (size_t)sa * D1 + f0);
            ushort4 pb = *(const ushort4*)(P + (size_t)sb * D1 + f0);
            float ea = __expf(lrelu(va));
            float eb = __expf(lrelu(vb));
            sum += ea + eb;
            acc0 += ea * bf2f(pa.x) + eb * bf2f(pb.x);
            acc1 += ea * bf2f(pa.y) + eb * bf2f(pb.y);
            acc2 += ea * bf2f(pa.z) + eb * bf2f(pb.z);
            acc3 += ea * bf2f(pa.w) + eb * bf2f(pb.w);
        }
        for (; s < s1; s++) {
            int sa = csr[s];
            float va = es[sa * 4 + head] + edv;
            ushort4 pa = *(const ushort4*)(P + (size_t)sa * D1 + f0);
            float ea = __expf(lrelu(va));
            sum += ea;
            acc0 += ea * bf2f(pa.x);
            acc1 += ea * bf2f(pa.y);
            acc2 += ea * bf2f(pa.z);
            acc3 += ea * bf2f(pa.w);
        }
        float inv = 1.f / sum;
        float a0 = acc0 * inv + bv0;
        float a1 = acc1 * inv + bv1;
        float a2 = acc2 * inv + bv2;
        float a3 = acc3 * inv + bv3;
        a0 = a0 > 0.f ? a0 : expm1f(a0);
        a1 = a1 > 0.f ? a1 : expm1f(a1);
        a2 = a2 > 0.f ? a2 : expm1f(a2);
        a3 = a3 > 0.f ? a3 : expm1f(a3);
        ushort4 hi4;
        hi4.x = f2bf(a0); hi4.y = f2bf(a1); hi4.z = f2bf(a2); hi4.w = f2bf(a3);
        *(ushort4*)(outHi + (size_t)dst * D1 + f0) = hi4;
    }
}

// ---------------- conv3: one-pass softmax + bf16 Q-gather + pool/classify ----------

__global__ __launch_bounds__(256) void aggregate3q_kernel(
    const unsigned short* __restrict__ Qb, const float* __restrict__ es,
    const float* __restrict__ ed, const int* __restrict__ rowoff,
    const int* __restrict__ csr, const int* __restrict__ batch,
    float* __restrict__ G) {
    int wave = threadIdx.x >> 6, lane = threadIdx.x & 63;
    int wid = blockIdx.x * 4 + wave;
    bool act = lane < NQ;
    int h = act ? (lane / NCLS) : 0;
    int q = act ? lane : 0;
    #pragma unroll 1
    for (int t = 0; t < 4; t++) {
        int dst = wid * 4 + t;
        int b = batch[dst];
        int s0 = rowoff[dst], s1 = rowoff[dst + 1];
        float edv = act ? ed[dst * H3 + h] : 0.f;
        float sum = 0.f, acc = 0.f;
        int s = s0;
        for (; s + 8 <= s1; s += 8) {
            int si[8];
            #pragma unroll
            for (int u = 0; u < 8; u++) si[u] = csr[s + u];
            float vv[8], qq[8];
            #pragma unroll
            for (int u = 0; u < 8; u++) {
                vv[u] = es[si[u] * H3 + h] + edv;
                qq[u] = bf2f(Qb[(size_t)si[u] * NQ + q]);
            }
            #pragma unroll
            for (int u = 0; u < 8; u++) {
                float e = __expf(lrelu(vv[u]));
                sum += e;
                acc += e * qq[u];
            }
        }
        for (; s + 2 <= s1; s += 2) {
            int sa = csr[s], sb = csr[s + 1];
            float va = es[sa * H3 + h] + edv;
            float vb = es[sb * H3 + h] + edv;
            float qa = bf2f(Qb[(size_t)sa * NQ + q]);
            float qb = bf2f(Qb[(size_t)sb * NQ + q]);
            float ea = __expf(lrelu(va));
            float eb = __expf(lrelu(vb));
            sum += ea + eb;
            acc += ea * qa + eb * qb;
        }
        for (; s < s1; s++) {
            int sa = csr[s];
            float va = es[sa * H3 + h] + edv;
            float qa = bf2f(Qb[(size_t)sa * NQ + q]);
            float ea = __expf(lrelu(va));
            sum += ea;
            acc += ea * qa;
        }
        acc *= 1.f / sum;
        float av = act ? acc : 0.f;
        float tot = av;
        #pragma unroll
        for (int h2 = 1; h2 < H3; h2++) tot += __shfl(av, lane + h2 * NCLS);
        if (lane < NCLS) atomicAdd(&G[b * NCLS + lane], tot);
    }
}

// ---------------- final: per-graph mean + folded b3 bias + bp ----------------

__global__ __launch_bounds__(64) void final_kernel(
    const float* __restrict__ G, const int* __restrict__ gs, const int* __restrict__ ge,
    const float* __restrict__ b3, const float* __restrict__ wp,
    const float* __restrict__ bp, float* __restrict__ out) {
    int b = blockIdx.x, tid = threadIdx.x;
    if (tid >= NCLS) return;
    int cntn = ge[b] - gs[b];
    float o = bp[tid];
    if (cntn > 0) {
        float bt = 0.f;
        for (int k = 0; k < O3; k++) {
            float bs = 0.f;
            #pragma unroll
            for (int h = 0; h < H3; h++) bs += b3[h * O3 + k];
            bt += bs * wp[k * NCLS + tid];
        }
        o += G[b * NCLS + tid] / (6.f * (float)cntn) + bt * (1.f / 6.f);
    }
    out[b * NCLS + tid] = o;
}

// ---------------- launch ----------------

extern "C" void kernel_launch(void* const* d_in, const int* in_sizes, int n_in,
                              void* d_out, int out_size, void* d_ws, size_t ws_size,
                              hipStream_t stream) {
    const int* x     = (const int*)d_in[0];
    const int* dep   = (const int*)d_in[1];
    const int* ei    = (const int*)d_in[2];
    const int* batch = (const int*)d_in[3];
    const float* nemb = (const float*)d_in[4];
    const float* demb = (const float*)d_in[5];
    const float* w1  = (const float*)d_in[6];
    const float* as1 = (const float*)d_in[7];
    const float* ad1 = (const float*)d_in[8];
    const float* b1  = (const float*)d_in[9];
    const float* w2  = (const float*)d_in[10];
    const float* as2 = (const float*)d_in[11];
    const float* ad2 = (const float*)d_in[12];
    const float* b2  = (const float*)d_in[13];
    const float* w3  = (const float*)d_in[14];
    const float* as3 = (const float*)d_in[15];
    const float* ad3 = (const float*)d_in[16];
    const float* b3  = (const float*)d_in[17];
    const float* wp  = (const float*)d_in[18];
    const float* bp  = (const float*)d_in[19];
    float* out = (float*)d_out;

    char* ws = (char*)d_ws;
    size_t off = 0;
    auto alloc = [&](size_t bytes) -> void* {
        void* p = ws + off;
        off += (bytes + 255) & ~(size_t)255;
        return p;
    };
    unsigned short* Hb   = (unsigned short*)alloc((size_t)NN * D1 * 2);     // H0 (stride 64) then H1/H2 (stride 256)
    unsigned short* H0lo = (unsigned short*)alloc((size_t)NN * EMB * 2);    // H0 lo (conv1 split A)
    unsigned short* W1hi = (unsigned short*)alloc((size_t)D1 * EMB * 2);
    unsigned short* W1lo = (unsigned short*)alloc((size_t)D1 * EMB * 2);
    unsigned short* W2b  = (unsigned short*)alloc((size_t)D1 * D1 * 2);
    unsigned short* W3b  = (unsigned short*)alloc((size_t)N3 * D1 * 2);
    unsigned short* Pb   = (unsigned short*)alloc((size_t)NN * D1 * 2);     // bf16 P (conv1/2)
    unsigned short* Qb   = (unsigned short*)alloc(((size_t)NN * NQ + 64) * 2);
    float* G    = (float*)alloc((size_t)NB * NCLS * 4);
    float* es   = (float*)alloc((size_t)NN * 6 * 4);
    float* ed   = (float*)alloc((size_t)NN * 6 * 4);
    int* cnt    = (int*)alloc((size_t)NN * 4);
    int* rowoff = (int*)alloc((size_t)(NN + 1) * 4);
    int* fillp  = (int*)alloc((size_t)NN * 4);
    int* csr    = (int*)alloc((size_t)ETOT * 4);
    int* gs     = (int*)alloc((size_t)NB * 4);
    int* ge     = (int*)alloc((size_t)NB * 4);

    // --- fused preprocessing (2 kernels) + scan + fill ---
    setup1_kernel<<<ceil_div(NN * EMB, 256), 256, 0, stream>>>(
        x, dep, nemb, demb, w1, Hb, H0lo, W1hi, W1lo, cnt, G, gs, ge);
    setup2_kernel<<<ceil_div(ETOT, 256), 256, 0, stream>>>(
        ei, batch, w2, w3, as3, ad3, wp, cnt, gs, ge, W2b, W3b);
    scan_kernel<<<1, 1024, 0, stream>>>(cnt, rowoff, fillp);
    fill_kernel<<<ceil_div(ETOT, 256), 256, 0, stream>>>(ei, fillp, csr);

    // --- conv1: [NN,64] -> [NN,256] split-bf16 GEMM, logits fused ---
    gemm_mfma_kernel<0, true><<<dim3(2, ceil_div(NN, 128)), 256, 0, stream>>>(
        Hb, H0lo, W1hi, W1lo, Pb, nullptr, es, ed, as1, ad1, NN, EMB, D1);
    aggregate12_kernel<<<NN / 16, 256, 0, stream>>>(Pb, es, ed, rowoff, csr, b1, Hb);

    // --- conv2: [NN,256] -> [NN,256] plain bf16 GEMM, logits fused ---
    gemm_mfma_kernel<0, false><<<dim3(2, ceil_div(NN, 128)), 256, 0, stream>>>(
        Hb, nullptr, W2b, nullptr, Pb, nullptr, es, ed, as2, ad2, NN, D1, D1);
    aggregate12_kernel<<<NN / 16, 256, 0, stream>>>(Pb, es, ed, rowoff, csr, b2, Hb);

    // --- conv3 folded: [NN,256] -> Qb[NN,60](bf16) + es/ed[NN,6], softmax+pool fused ---
    gemm_mfma_kernel<1, false><<<dim3(1, ceil_div(NN, 128)), 256, 0, stream>>>(
        Hb, nullptr, W3b, nullptr, nullptr, Qb, es, ed, nullptr, nullptr, NN, D1, N3);
    aggregate3q_kernel<<<NN / 16, 256, 0, stream>>>(Qb, es, ed, rowoff, csr, batch, G);

    // --- final classifier ---
    final_kernel<<<NB, 64, 0, stream>>>(G, gs, ge, b3, wp, bp, out);
}